// Round 1
// 177.609 us; speedup vs baseline: 1.0711x; 1.0711x over previous
//
#include <hip/hip_runtime.h>
#include <math.h>

typedef _Float16 f16;
typedef _Float16 f16x8 __attribute__((ext_vector_type(8)));
typedef float f32x4 __attribute__((ext_vector_type(4)));

// ---------------------------------------------------------------------------
// Prep: W3t[c][k] = f16(W3[k][c])  (1024x128), W2t[c][k] = f16(W2[k][c])
// (128x64), wpk[k][4] = {W1[0][k], W1[1][k], W1[2][k], b1[k]} fp32.
// Makes MFMA B-fragments contiguous 16B loads and layer-1 weights a single
// b128 broadcast read per (k-octet element).
// ---------------------------------------------------------------------------
__global__ __launch_bounds__(256) void prep_weights(
    const float* __restrict__ W1, const float* __restrict__ b1,
    const float* __restrict__ W2, const float* __restrict__ W3,
    f16* __restrict__ W2t, f16* __restrict__ W3t, float* __restrict__ wpk)
{
    int idx = blockIdx.x * 256 + threadIdx.x;
    int stride = gridDim.x * 256;
    for (int i = idx; i < 1024 * 128; i += stride) {
        int c = i >> 7, k = i & 127;
        W3t[i] = (f16)W3[k * 1024 + c];
    }
    for (int i = idx; i < 128 * 64; i += stride) {
        int c = i >> 6, k = i & 63;
        W2t[i] = (f16)W2[k * 128 + c];
    }
    if (idx < 256) {
        int k = idx >> 2, c = idx & 3;
        wpk[idx] = (c < 3) ? W1[c * 64 + k] : b1[k];
    }
}

// ---------------------------------------------------------------------------
// Fused PointNet: layers 1-3 + max-pool, one block per batch.
// 512 threads = 8 waves. Per 128-point chunk:
//   phase A: h1 = relu(x@W1+b1) in VALU regs -> h2 = relu(h1@W2+b2) via MFMA
//            -> LDS tile [128][136] f16 (double-buffered, 1 barrier/chunk)
//   phase B: layer3 MFMA from LDS tile; each wave owns a 128-col strip with
//            W3 B-fragments resident (128 VGPRs) -> per-col running max.
// A-tile read once per wave per chunk (32 KB); 128-col strips double the
// FLOP/LDS-byte vs the old 64-col kernel -> LDS and MFMA pipes balanced.
// No global traffic in the main loop at all (x staged up front, W in regs).
// ---------------------------------------------------------------------------
__global__ __launch_bounds__(512, 2) void pointnet_fused(
    const float* __restrict__ x,   // [B][1024][3]
    const float* __restrict__ wpk, // [64][4] {w0,w1,w2,b1}
    const f16* __restrict__ W2t,   // [128 c][64 k]
    const float* __restrict__ b2,  // [128]
    const f16* __restrict__ W3t,   // [1024 c][128 k]
    const float* __restrict__ b3,  // [1024]
    float* __restrict__ g)         // [B][1024]
{
    __shared__ float xs[1024 * 3];                   // 12 KB, whole batch
    __shared__ __align__(16) float wls[288];         // staggered wpack
    __shared__ float b2s[128];
    __shared__ __align__(16) f16 h2s[2][128 * 136];  // 2 x 34 KB, +8 f16 pad

    int b = blockIdx.x;
    int tid = threadIdx.x;
    int lane = tid & 63, w = tid >> 6;        // wave id 0..7
    int lrow = lane & 15, quad = lane >> 4;
    int wr2 = w & 3, wc2 = w >> 2;            // layer2 role: 32-row, 64-col tile

    // ---- B fragments: issued first so latency hides under staging ----------
    // layer3: wave strip = cols [w*128, w*128+128)
    f16x8 bf3[8][4];  // [ct][kc]
    {
        const f16* base = W3t + (size_t)(w * 128 + lrow) * 128 + quad * 8;
#pragma unroll
        for (int ct = 0; ct < 8; ct++)
#pragma unroll
            for (int kc = 0; kc < 4; kc++)
                bf3[ct][kc] = *(const f16x8*)(base + ct * 16 * 128 + kc * 32);
    }
    // layer2
    f16x8 bf2[4][2];  // [ct][kc2]
    {
        const f16* base = W2t + (size_t)(wc2 * 64 + lrow) * 64 + quad * 8;
#pragma unroll
        for (int ct = 0; ct < 4; ct++)
#pragma unroll
            for (int kc2 = 0; kc2 < 2; kc2++)
                bf2[ct][kc2] = *(const f16x8*)(base + ct * 16 * 64 + kc2 * 32);
    }

    // ---- stage x (whole batch), layer1 weights (staggered), b2 -------------
    {
        const float* xb = x + (size_t)b * 3072;
        for (int i = tid; i < 3072; i += 512) xs[i] = xb[i];
        if (tid < 256) {
            int k = tid >> 2, c = tid & 3;
            // stagger: quad-strided b128 reads land on distinct bank groups
            wls[(k + (k >> 3)) * 4 + c] = wpk[tid];
        }
        if (tid >= 256 && tid < 384) b2s[tid - 256] = b2[tid - 256];
    }
    __syncthreads();

    const f32x4 z4 = {0.f, 0.f, 0.f, 0.f};
    float cmax[8];
#pragma unroll
    for (int ct = 0; ct < 8; ct++) cmax[ct] = -3.0e38f;

    // phase A: layers 1+2 for `chunk` -> h2s[chunk&1]
    auto phaseA = [&](int chunk) {
        f16* hb = h2s[chunk & 1];
        int p0 = chunk * 128 + wr2 * 32 + lrow;
        float x00 = xs[p0 * 3], x01 = xs[p0 * 3 + 1], x02 = xs[p0 * 3 + 2];
        int p1 = p0 + 16;
        float x10 = xs[p1 * 3], x11 = xs[p1 * 3 + 1], x12 = xs[p1 * 3 + 2];
        f32x4 acc2[2][4];
#pragma unroll
        for (int kc2 = 0; kc2 < 2; kc2++) {
            f16x8 af2[2];
#pragma unroll
            for (int j = 0; j < 8; j++) {
                int k = kc2 * 32 + quad * 8 + j;
                f32x4 wv = *(const f32x4*)&wls[(k + (k >> 3)) * 4];
                float v0 = fmaf(x02, wv[2], fmaf(x01, wv[1], fmaf(x00, wv[0], wv[3])));
                float v1 = fmaf(x12, wv[2], fmaf(x11, wv[1], fmaf(x10, wv[0], wv[3])));
                af2[0][j] = (f16)fmaxf(v0, 0.f);
                af2[1][j] = (f16)fmaxf(v1, 0.f);
            }
#pragma unroll
            for (int rt = 0; rt < 2; rt++)
#pragma unroll
                for (int ct = 0; ct < 4; ct++)
                    acc2[rt][ct] = __builtin_amdgcn_mfma_f32_16x16x32_f16(
                        af2[rt], bf2[ct][kc2], kc2 ? acc2[rt][ct] : z4, 0, 0, 0);
        }
        // bias + relu + cvt -> LDS tile
#pragma unroll
        for (int rt = 0; rt < 2; rt++)
#pragma unroll
            for (int ct = 0; ct < 4; ct++) {
                int col = wc2 * 64 + ct * 16 + lrow;
                float bb = b2s[col];
                int rowb = wr2 * 32 + rt * 16 + quad * 4;
#pragma unroll
                for (int r = 0; r < 4; r++)
                    hb[(rowb + r) * 136 + col] = (f16)fmaxf(acc2[rt][ct][r] + bb, 0.f);
            }
    };

    // phase B: layer3 MFMA from h2s[chunk&1], running col-max
    auto phaseB = [&](int chunk) {
        const f16* hb = h2s[chunk & 1];
#pragma unroll
        for (int rt = 0; rt < 8; rt++) {
            f32x4 acc[8];
#pragma unroll
            for (int kc = 0; kc < 4; kc++) {
                f16x8 af = *(const f16x8*)(hb + (rt * 16 + lrow) * 136 + kc * 32 + quad * 8);
#pragma unroll
                for (int ct = 0; ct < 8; ct++)
                    acc[ct] = __builtin_amdgcn_mfma_f32_16x16x32_f16(
                        af, bf3[ct][kc], kc ? acc[ct] : z4, 0, 0, 0);
            }
#pragma unroll
            for (int ct = 0; ct < 8; ct++) {
                float m01 = fmaxf(acc[ct][0], acc[ct][1]);
                float m23 = fmaxf(acc[ct][2], acc[ct][3]);
                cmax[ct] = fmaxf(cmax[ct], fmaxf(m01, m23));  // -> v_max3
            }
        }
    };

    phaseA(0);
    __syncthreads();
#pragma unroll 1
    for (int c = 0; c < 7; c++) {
        phaseA(c + 1);   // fills other buffer; overlaps phaseB(c) below barrier
        phaseB(c);
        __syncthreads();
    }
    phaseB(7);

    // cross-quad reduce (quads hold disjoint row subsets of same col)
#pragma unroll
    for (int ct = 0; ct < 8; ct++) {
        cmax[ct] = fmaxf(cmax[ct], __shfl_xor(cmax[ct], 16, 64));
        cmax[ct] = fmaxf(cmax[ct], __shfl_xor(cmax[ct], 32, 64));
    }
    if (quad == 0) {
#pragma unroll
        for (int ct = 0; ct < 8; ct++) {
            int cg = w * 128 + ct * 16 + lrow;
            g[(size_t)b * 1024 + cg] = fmaxf(cmax[ct] + b3[cg], 0.f);
        }
    }
}

// ---------------------------------------------------------------------------
// Head layer 1 partials: zp1[kc][b][c] = sum_{k in chunk} g[b][k]*Wh1[k][c].
// ---------------------------------------------------------------------------
__global__ __launch_bounds__(256) void head_l1(
    const float* __restrict__ g, const float* __restrict__ Wh1,
    float* __restrict__ zp1)
{
    __shared__ float gs4[4][256];
    int cb = blockIdx.x, bb = blockIdx.y, kc = blockIdx.z;
    int tid = threadIdx.x;
    int b0 = bb * 4;
    int kbase = kc * 256;
#pragma unroll
    for (int j = 0; j < 4; j++) {
        int i = tid + j * 256;
        gs4[i >> 8][i & 255] = g[(size_t)(b0 + (i >> 8)) * 1024 + kbase + (i & 255)];
    }
    __syncthreads();

    int c = cb * 256 + tid;
    float acc[4] = {0.f, 0.f, 0.f, 0.f};
#pragma unroll 1
    for (int k = 0; k < 256; k += 8) {
        float w[8];
#pragma unroll
        for (int j = 0; j < 8; j++) w[j] = Wh1[(size_t)(kbase + k + j) * 512 + c];
#pragma unroll
        for (int r = 0; r < 4; r++) {
            float4 a = *(const float4*)&gs4[r][k];
            float4 bq = *(const float4*)&gs4[r][k + 4];
            acc[r] = fmaf(a.x, w[0], acc[r]);
            acc[r] = fmaf(a.y, w[1], acc[r]);
            acc[r] = fmaf(a.z, w[2], acc[r]);
            acc[r] = fmaf(a.w, w[3], acc[r]);
            acc[r] = fmaf(bq.x, w[4], acc[r]);
            acc[r] = fmaf(bq.y, w[5], acc[r]);
            acc[r] = fmaf(bq.z, w[6], acc[r]);
            acc[r] = fmaf(bq.w, w[7], acc[r]);
        }
    }
#pragma unroll
    for (int r = 0; r < 4; r++)
        zp1[((size_t)kc * 256 + b0 + r) * 512 + c] = acc[r];
}

// ---------------------------------------------------------------------------
// Head layer 2 partials, z1-reduce fused into staging.
// ---------------------------------------------------------------------------
__global__ __launch_bounds__(256) void head_l2(
    const float* __restrict__ zp1, const float* __restrict__ bh1,
    const float* __restrict__ Wh2, float* __restrict__ zp2)
{
    __shared__ float z1s[2][128];
    int bb = blockIdx.x, kc2 = blockIdx.y;
    int tid = threadIdx.x;
    int b0 = bb * 2;
    int kb = kc2 * 128;
    {
        int row = tid >> 7, kk = tid & 127;
        int col = kb + kk;
        float v = bh1[col];
#pragma unroll
        for (int j = 0; j < 4; j++)
            v += zp1[((size_t)j * 256 + b0 + row) * 512 + col];
        z1s[row][kk] = fmaxf(v, 0.f);
    }
    __syncthreads();

    int c = tid;
    float acc0 = 0.f, acc1 = 0.f;
#pragma unroll 1
    for (int k = 0; k < 128; k += 8) {
        float w[8];
#pragma unroll
        for (int j = 0; j < 8; j++) w[j] = Wh2[(size_t)(kb + k + j) * 256 + c];
        float4 a0 = *(const float4*)&z1s[0][k];
        float4 a1 = *(const float4*)&z1s[0][k + 4];
        float4 d0 = *(const float4*)&z1s[1][k];
        float4 d1 = *(const float4*)&z1s[1][k + 4];
        acc0 = fmaf(a0.x, w[0], acc0);  acc1 = fmaf(d0.x, w[0], acc1);
        acc0 = fmaf(a0.y, w[1], acc0);  acc1 = fmaf(d0.y, w[1], acc1);
        acc0 = fmaf(a0.z, w[2], acc0);  acc1 = fmaf(d0.z, w[2], acc1);
        acc0 = fmaf(a0.w, w[3], acc0);  acc1 = fmaf(d0.w, w[3], acc1);
        acc0 = fmaf(a1.x, w[4], acc0);  acc1 = fmaf(d1.x, w[4], acc1);
        acc0 = fmaf(a1.y, w[5], acc0);  acc1 = fmaf(d1.y, w[5], acc1);
        acc0 = fmaf(a1.z, w[6], acc0);  acc1 = fmaf(d1.z, w[6], acc1);
        acc0 = fmaf(a1.w, w[7], acc0);  acc1 = fmaf(d1.w, w[7], acc1);
    }
    zp2[((size_t)kc2 * 256 + b0    ) * 256 + c] = acc0;
    zp2[((size_t)kc2 * 256 + b0 + 1) * 256 + c] = acc1;
}

// ---------------------------------------------------------------------------
// SVD -> SO(3) projection, fp64 Jacobi on M^T M (per-thread serial)
// ---------------------------------------------------------------------------
__device__ inline void jrot(double S[3][3], double V[3][3], int p, int q)
{
    double apq = S[p][q];
    if (fabs(apq) < 1e-36) return;
    double tau = (S[q][q] - S[p][p]) / (2.0 * apq);
    double t = (tau >= 0.0 ? 1.0 : -1.0) / (fabs(tau) + sqrt(1.0 + tau * tau));
    double c = 1.0 / sqrt(1.0 + t * t);
    double s = t * c;
    for (int k = 0; k < 3; k++) {
        double skp = S[k][p], skq = S[k][q];
        S[k][p] = c * skp - s * skq;  S[k][q] = s * skp + c * skq;
    }
    for (int k = 0; k < 3; k++) {
        double spk = S[p][k], sqk = S[q][k];
        S[p][k] = c * spk - s * sqk;  S[q][k] = s * spk + c * sqk;
    }
    for (int k = 0; k < 3; k++) {
        double vkp = V[k][p], vkq = V[k][q];
        V[k][p] = c * vkp - s * vkq;  V[k][q] = s * vkp + c * vkq;
    }
}

__device__ void svd_so3(const float* Mf, float* Rout)
{
    double M[3][3], S[3][3], V[3][3];
    for (int i = 0; i < 3; i++)
        for (int j = 0; j < 3; j++) M[i][j] = (double)Mf[3 * i + j];
    for (int i = 0; i < 3; i++)
        for (int j = 0; j < 3; j++)
            S[i][j] = M[0][i] * M[0][j] + M[1][i] * M[1][j] + M[2][i] * M[2][j];
    for (int i = 0; i < 3; i++)
        for (int j = 0; j < 3; j++) V[i][j] = (i == j) ? 1.0 : 0.0;
    for (int it = 0; it < 10; it++) {
        jrot(S, V, 0, 1); jrot(S, V, 0, 2); jrot(S, V, 1, 2);
    }
    double lam[3] = {S[0][0], S[1][1], S[2][2]};
    int i0 = 0, i1 = 1, i2 = 2, tt;
    if (lam[i0] < lam[i1]) { tt = i0; i0 = i1; i1 = tt; }
    if (lam[i0] < lam[i2]) { tt = i0; i0 = i2; i2 = tt; }
    if (lam[i1] < lam[i2]) { tt = i1; i1 = i2; i2 = tt; }
    double v0[3], v1[3], v2[3];
    for (int k = 0; k < 3; k++) { v0[k] = V[k][i0]; v1[k] = V[k][i1]; v2[k] = V[k][i2]; }
    double u1[3], u2[3], u3[3];
    for (int i = 0; i < 3; i++) u1[i] = M[i][0] * v0[0] + M[i][1] * v0[1] + M[i][2] * v0[2];
    double n1 = sqrt(u1[0] * u1[0] + u1[1] * u1[1] + u1[2] * u1[2]) + 1e-300;
    for (int i = 0; i < 3; i++) u1[i] /= n1;
    for (int i = 0; i < 3; i++) u2[i] = M[i][0] * v1[0] + M[i][1] * v1[1] + M[i][2] * v1[2];
    double d12 = u1[0] * u2[0] + u1[1] * u2[1] + u1[2] * u2[2];
    for (int i = 0; i < 3; i++) u2[i] -= d12 * u1[i];
    double n2 = sqrt(u2[0] * u2[0] + u2[1] * u2[1] + u2[2] * u2[2]) + 1e-300;
    for (int i = 0; i < 3; i++) u2[i] /= n2;
    u3[0] = u1[1] * u2[2] - u1[2] * u2[1];
    u3[1] = u1[2] * u2[0] - u1[0] * u2[2];
    u3[2] = u1[0] * u2[1] - u1[1] * u2[0];
    double c12x = v1[1] * v2[2] - v1[2] * v2[1];
    double c12y = v1[2] * v2[0] - v1[0] * v2[2];
    double c12z = v1[0] * v2[1] - v1[1] * v2[0];
    double detV = v0[0] * c12x + v0[1] * c12y + v0[2] * c12z;
    for (int i = 0; i < 3; i++)
        for (int j = 0; j < 3; j++)
            Rout[3 * i + j] = (float)(u1[i] * v0[j] + u2[i] * v1[j] + detV * u3[i] * v2[j]);
}

// ---------------------------------------------------------------------------
// Head tail: z2-reduce + (z2 @ Wh3 + bh3) + SVD. Wh3 staged in LDS.
// ---------------------------------------------------------------------------
__global__ __launch_bounds__(128) void head_l3_svd(
    const float* __restrict__ zp2, const float* __restrict__ bh2,
    const float* __restrict__ Wh3, const float* __restrict__ bh3,
    float* __restrict__ out)
{
    __shared__ float z2s[8][256];
    __shared__ float wh3s[2304];
    __shared__ float raws[8][12];
    int b0 = blockIdx.x * 8;
    int tid = threadIdx.x;

    for (int i = tid; i < 2304; i += 128) wh3s[i] = Wh3[i];
    for (int i = tid; i < 8 * 256; i += 128) {
        int row = i >> 8, kk = i & 255;
        float v = bh2[kk];
#pragma unroll
        for (int j = 0; j < 4; j++)
            v += zp2[((size_t)j * 256 + b0 + row) * 256 + kk];
        z2s[row][kk] = fmaxf(v, 0.f);
    }
    __syncthreads();

    if (tid < 72) {
        int r = tid / 9, c = tid % 9;
        float acc = bh3[c];
#pragma unroll 8
        for (int k = 0; k < 256; k++) acc = fmaf(z2s[r][k], wh3s[k * 9 + c], acc);
        raws[r][c] = acc;
    }
    __syncthreads();

    if (tid < 8) svd_so3(&raws[tid][0], out + (size_t)(b0 + tid) * 9);
}

// ---------------------------------------------------------------------------
extern "C" void kernel_launch(void* const* d_in, const int* in_sizes, int n_in,
                              void* d_out, int out_size, void* d_ws, size_t ws_size,
                              hipStream_t stream)
{
    const float* x   = (const float*)d_in[0];
    const float* W1  = (const float*)d_in[1];
    const float* b1  = (const float*)d_in[2];
    const float* W2  = (const float*)d_in[3];
    const float* b2  = (const float*)d_in[4];
    const float* W3  = (const float*)d_in[5];
    const float* b3  = (const float*)d_in[6];
    const float* Wh1 = (const float*)d_in[7];
    const float* bh1 = (const float*)d_in[8];
    const float* Wh2 = (const float*)d_in[9];
    const float* bh2 = (const float*)d_in[10];
    const float* Wh3 = (const float*)d_in[11];
    const float* bh3 = (const float*)d_in[12];
    float* out = (float*)d_out;

    char* ws = (char*)d_ws;
    f16*   W2t = (f16*)ws;                       // 16 KB
    f16*   W3t = (f16*)(ws + 65536);             // 256 KB
    float* wpk = (float*)(ws + 524288);          // 1 KB
    float* g   = (float*)(ws + 1048576);         // 1 MB
    float* zp1 = (float*)(ws + 2097152);         // 2 MB
    float* zp2 = (float*)(ws + 4194304);         // 1 MB

    prep_weights<<<128, 256, 0, stream>>>(W1, b1, W2, W3, W2t, W3t, wpk);
    pointnet_fused<<<256, 512, 0, stream>>>(x, wpk, W2t, b2, W3t, b3, g);
    dim3 gridH1(2, 64, 4);
    head_l1<<<gridH1, 256, 0, stream>>>(g, Wh1, zp1);
    dim3 gridH2(128, 4);
    head_l2<<<gridH2, 256, 0, stream>>>(zp1, bh1, Wh2, zp2);
    head_l3_svd<<<32, 128, 0, stream>>>(zp2, bh2, Wh3, bh3, out);
}